// Round 7
// baseline (483.152 us; speedup 1.0000x reference)
//
#include <hip/hip_runtime.h>

// Problem constants
#define B_     32
#define NOTES_ 78
#define T_     128
#define IN_    80
#define H_     128
#define NSEQ_  (B_*NOTES_)    // 2496
#define MBLK   16             // sequences per block (A-tile rows of 16x16x32 MFMA)
#define NBLK1  (NSEQ_/MBLK)   // 156 blocks
#define SEQ2_  (B_*T_)        // 4096 note-LSTM sequences
#define XN8    (NSEQ_*T_*IN_/8)
#define SHSTR  136            // sH row stride in shorts (272 B, 16B-aligned for b128)

typedef __attribute__((ext_vector_type(8))) short short8;   // 8 x bf16 (4 VGPRs)
typedef __attribute__((ext_vector_type(4))) float f32x4;

__device__ __forceinline__ unsigned short f2bf(float f) {
    unsigned u; __builtin_memcpy(&u, &f, 4);
    u += 0x7fffu + ((u >> 16) & 1u);          // RNE
    return (unsigned short)(u >> 16);
}
__device__ __forceinline__ short8 pack8(const float* p) {   // init-time only
    short8 r;
    #pragma unroll
    for (int k = 0; k < 8; ++k) r[k] = (short)f2bf(p[k]);
    return r;
}
__device__ __forceinline__ float rcpf(float x)  { return __builtin_amdgcn_rcpf(x); }
__device__ __forceinline__ float sigm(float x)  { return rcpf(1.f + __expf(-x)); }
__device__ __forceinline__ float tanhr(float x) { return 2.f * rcpf(1.f + __expf(-2.f*x)) - 1.f; }

// ---------------------------------------------------------------------------
// Phase A: convert x f32 -> bf16 (memory-bound, ~153 MB traffic, ~27 us).
// ---------------------------------------------------------------------------
__global__ __launch_bounds__(256) void xcvt_kernel(
    const float* __restrict__ x, unsigned short* __restrict__ xb)
{
    const int i = blockIdx.x * 256 + threadIdx.x;
    if (i < XN8) {
        const f32x4 a = *(const f32x4*)(x + (size_t)i * 8);
        const f32x4 b = *(const f32x4*)(x + (size_t)i * 8 + 4);
        short8 r;
        #pragma unroll
        for (int k = 0; k < 4; ++k) { r[k] = (short)f2bf(a[k]); r[4+k] = (short)f2bf(b[k]); }
        *(short8*)(xb + (size_t)i * 8) = r;
    }
}

// ---------------------------------------------------------------------------
// Fused time LSTM + note-gate pre-activations.
//
// THIS ROUND: 16 waves / 1024 thr / block -> 4 waves per SIMD (was 2).
// Wave (cg = w&7, half = w>>3) owns h-cols [16cg,16cg+16) and TWO gates
// (half0: i,f; half1: g,o).  Per-wave weight set halves (56 VGPR) so the
// whole live set fits the 128-reg budget a 16-wave block mandates (the old
// 112-reg weight set forced 2 waves/SIMD and left ~50% of the step as
// unfillable stall -- rounds 5/6 showed stall, not pipe, dominates).
// The two missing gates per cell are exchanged via a 16KB LDS buffer
// (1 b128 write + 1 b128 read per lane per step); each lane updates 2 cells
// (was 4).  Two raw lgkmcnt-only barriers per step: B1 = gate exchange,
// B2 = h visibility.  accX/prefetch is pre-B1 for half0, post-B1 for half1
// (cross-barrier matrix/VALU overlap).  wn lives in LDS (only the rotating
// Gn-duty wave reads it); Gn addressing recomputed in-branch (reg savings).
// ---------------------------------------------------------------------------
#define ACCX_AND_PREFETCH                                                              \
    if (t + 1 < T_) {                                                                  \
        __builtin_amdgcn_s_setprio(1);                                                 \
        _Pragma("unroll")                                                              \
        for (int gl = 0; gl < 2; ++gl) {                                               \
            accX[gl] = (f32x4){bg2[gl], bg2[gl], bg2[gl], bg2[gl]};                    \
            accX[gl] = __builtin_amdgcn_mfma_f32_16x16x32_bf16(ax0, wf[gl][0], accX[gl], 0, 0, 0); \
            accX[gl] = __builtin_amdgcn_mfma_f32_16x16x32_bf16(ax1, wf[gl][1], accX[gl], 0, 0, 0); \
            accX[gl] = __builtin_amdgcn_mfma_f32_16x16x32_bf16(ax2, wf[gl][2], accX[gl], 0, 0, 0); \
        }                                                                              \
        __builtin_amdgcn_s_setprio(0);                                                 \
    }                                                                                  \
    if (t + 2 < T_) {                                                                  \
        if (XB16) {                                                                    \
            const unsigned short* p = xrb + (t + 2) * IN_;                             \
            ax0 = *(const short8*)(p + quad * 8);                                      \
            ax1 = *(const short8*)(p + 32 + quad * 8);                                 \
            if (quad < 2) ax2 = *(const short8*)(p + 64 + quad * 8);                   \
        } else {                                                                       \
            const float* p = xrf + (t + 2) * IN_;                                      \
            ax0 = pack8(p + quad * 8);                                                 \
            ax1 = pack8(p + 32 + quad * 8);                                            \
            if (quad < 2) ax2 = pack8(p + 64 + quad * 8);                              \
        }                                                                              \
    }

// Note-gate tile for step TM1 (rotating duty over all 16 waves); wn read from
// LDS, output addressing recomputed in-branch (1/16 duty -> cheap).
#define GN_TILE(TM1)                                                                   \
    if (wave == ((TM1) & 15)) {                                                        \
        short8 wnk[4];                                                                 \
        _Pragma("unroll")                                                              \
        for (int kt = 0; kt < 4; ++kt)                                                 \
            wnk[kt] = *(const short8*)(sWn + ((kt * 16 + m16) * 4 + quad) * 8);        \
        f32x4 an = (f32x4){0.f, 0.f, 0.f, 0.f};                                        \
        _Pragma("unroll")                                                              \
        for (int kt = 0; kt < 4; ++kt)                                                 \
            an = __builtin_amdgcn_mfma_f32_16x16x32_bf16(ah[kt], wnk[kt], an, 0, 0, 0);\
        if (m16 < 8) {                                                                 \
            _Pragma("unroll")                                                          \
            for (int r = 0; r < 4; ++r) {                                              \
                const int sq = seq0 + quad * 4 + r;                                    \
                const int bb = sq / NOTES_;                                            \
                const int nn = sq - bb * NOTES_;                                       \
                Gn[((unsigned)bb * (T_ * NOTES_) + (unsigned)nn) * 8u + (unsigned)m16  \
                   + (unsigned)(TM1) * (NOTES_ * 8)] = an[r] + bns;                    \
            }                                                                          \
        }                                                                              \
    }

template<bool XB16>
__global__ __launch_bounds__(1024)
void time_lstm_kernel(
    const void* __restrict__ xin,    // [NSEQ][T][IN] bf16 (XB16) or f32
    const float* __restrict__ Wih,   // [512][80]  f32
    const float* __restrict__ Whh,   // [512][128] f32
    const float* __restrict__ bih,   // [512] f32
    const float* __restrict__ bhh,   // [512] f32
    const float* __restrict__ Wn,    // [8][128] f32 (Wih_n)
    const float* __restrict__ bn1,   // [8] f32
    const float* __restrict__ bn2,   // [8] f32
    float* __restrict__ Gn)          // [B*T][NOTES][8] f32 (ws)
{
    __shared__ unsigned short sH[2][MBLK * SHSTR];   // 8704 B (double-buffered h)
    __shared__ float sX[8 * 2 * 64 * 4];             // 16384 B gate-exchange
    __shared__ unsigned short sWn[4 * 16 * 4 * 8];   // 4096 B note-gate weights

    const int tid  = threadIdx.x;
    const int wave = tid >> 6, lane = tid & 63;
    const int m16  = lane & 15, quad = lane >> 4;
    const int cg   = wave & 7, half = wave >> 3;
    const int seq0 = blockIdx.x * MBLK;
    const int j    = cg * 16 + m16;            // this lane's h-column

    for (int i = tid; i < 2 * MBLK * SHSTR; i += 1024)
        ((unsigned short*)sH)[i] = 0;          // h(-1) = 0
    for (int i = tid; i < 4 * 16 * 4 * 8; i += 1024) {
        const int e = i & 7, q = (i >> 3) & 3, m = (i >> 5) & 15, kt = i >> 9;
        sWn[i] = (m < 8) ? f2bf(Wn[m * H_ + kt * 32 + q * 8 + e]) : (unsigned short)0;
    }

    // ---- weights for MY two gates (half0: i,f = gates 0,1; half1: g,o) ----
    const short8 zero8 = (short8){0,0,0,0,0,0,0,0};
    short8 wf[2][3], hf[2][4];
    float  bg2[2];
    #pragma unroll
    for (int gl = 0; gl < 2; ++gl) {
        const int n = (half * 2 + gl) * H_ + j;    // gate column in [0,512)
        #pragma unroll
        for (int kt = 0; kt < 3; ++kt) {
            const int k = kt * 32 + quad * 8;
            wf[gl][kt] = (k < IN_) ? pack8(Wih + n * IN_ + k) : zero8;
        }
        #pragma unroll
        for (int kt = 0; kt < 4; ++kt)
            hf[gl][kt] = pack8(Whh + n * H_ + kt * 32 + quad * 8);
        bg2[gl] = bih[n] + bhh[n];
    }
    const float bns = (m16 < 8) ? (bn1[m16] + bn2[m16]) : 0.f;

    // ---- exchange slots ----
    const int xw_off = ((cg * 2 + half) * 64 + lane) * 4;
    const int xr_off = ((cg * 2 + (half ^ 1)) * 64 + lane) * 4;

    // ---- x A-fragment pointers (lane m16 -> sequence row) ----
    const float* xrf = XB16 ? nullptr
        : ((const float*)xin + (size_t)(seq0 + m16) * T_ * IN_);
    const unsigned short* xrb = XB16
        ? ((const unsigned short*)xin + (size_t)(seq0 + m16) * T_ * IN_) : nullptr;

    short8 ax0, ax1, ax2 = zero8;
    if (XB16) {                                 // load x(0)
        const unsigned short* p = xrb;
        ax0 = *(const short8*)(p + quad * 8);
        ax1 = *(const short8*)(p + 32 + quad * 8);
        if (quad < 2) ax2 = *(const short8*)(p + 64 + quad * 8);
    } else {
        const float* p = xrf;
        ax0 = pack8(p + quad * 8);
        ax1 = pack8(p + 32 + quad * 8);
        if (quad < 2) ax2 = pack8(p + 64 + quad * 8);
    }

    // prologue: accX(0) = bias + x(0).Wih^T (my 2 gates)
    f32x4 accX[2];
    #pragma unroll
    for (int gl = 0; gl < 2; ++gl) {
        accX[gl] = (f32x4){bg2[gl], bg2[gl], bg2[gl], bg2[gl]};
        accX[gl] = __builtin_amdgcn_mfma_f32_16x16x32_bf16(ax0, wf[gl][0], accX[gl], 0, 0, 0);
        accX[gl] = __builtin_amdgcn_mfma_f32_16x16x32_bf16(ax1, wf[gl][1], accX[gl], 0, 0, 0);
        accX[gl] = __builtin_amdgcn_mfma_f32_16x16x32_bf16(ax2, wf[gl][2], accX[gl], 0, 0, 0);
    }
    if (XB16) {                                 // load x(1)
        const unsigned short* p = xrb + IN_;
        ax0 = *(const short8*)(p + quad * 8);
        ax1 = *(const short8*)(p + 32 + quad * 8);
        if (quad < 2) ax2 = *(const short8*)(p + 64 + quad * 8);
    } else {
        const float* p = xrf + IN_;
        ax0 = pack8(p + quad * 8);
        ax1 = pack8(p + 32 + quad * 8);
        if (quad < 2) ax2 = pack8(p + 64 + quad * 8);
    }

    float cst[2] = {0.f, 0.f};                  // my 2 cells' state (rows half*2+rr)

    __syncthreads();                            // init fence (once; full drain ok)

    for (int t = 0; t < T_; ++t) {
        const unsigned short* sHr = sH[t & 1];          // holds h(t-1)
        unsigned short*       sHw = sH[(t & 1) ^ 1];    // receives h(t)

        // h(t-1) A-fragments (identical across waves)
        short8 ah[4];
        #pragma unroll
        for (int kt = 0; kt < 4; ++kt)
            ah[kt] = *(const short8*)(sHr + m16 * SHSTR + kt * 32 + quad * 8);

        // main gate MFMAs: my 2 gates, start from accX, 4-deep h chain
        f32x4 acc[2];
        __builtin_amdgcn_s_setprio(1);
        #pragma unroll
        for (int gl = 0; gl < 2; ++gl) {
            acc[gl] = accX[gl];
            #pragma unroll
            for (int kt = 0; kt < 4; ++kt)
                acc[gl] = __builtin_amdgcn_mfma_f32_16x16x32_bf16(ah[kt], hf[gl][kt], acc[gl], 0, 0, 0);
        }
        __builtin_amdgcn_s_setprio(0);

        // gate exchange write: my 2 gates for the PARTNER's rows
        f32x4 xw;
        if (half == 0) xw = (f32x4){acc[0][2], acc[0][3], acc[1][2], acc[1][3]}; // i,f rows 2,3
        else           xw = (f32x4){acc[0][0], acc[0][1], acc[1][0], acc[1][1]}; // g,o rows 0,1
        *(f32x4*)(sX + xw_off) = xw;

        if (half == 0) {                        // matrix filler pre-B1
            ACCX_AND_PREFETCH
            if (t > 0) GN_TILE(t - 1)
        }

        // B1: gates visible (lgkmcnt only; global traffic stays in flight)
        __builtin_amdgcn_sched_barrier(0);
        asm volatile("s_waitcnt lgkmcnt(0)" ::: "memory");
        __builtin_amdgcn_s_barrier();
        __builtin_amdgcn_sched_barrier(0);

        const f32x4 rd = *(const f32x4*)(sX + xr_off);

        // assemble 4 gates for MY 2 cells (rows quad*4 + half*2 + rr)
        float gi[2], gf[2], gg[2], go[2];
        if (half == 0) {
            gi[0] = acc[0][0]; gi[1] = acc[0][1];
            gf[0] = acc[1][0]; gf[1] = acc[1][1];
            gg[0] = rd[0];     gg[1] = rd[1];
            go[0] = rd[2];     go[1] = rd[3];
        } else {
            gg[0] = acc[0][2]; gg[1] = acc[0][3];
            go[0] = acc[1][2]; go[1] = acc[1][3];
            gi[0] = rd[0];     gi[1] = rd[1];
            gf[0] = rd[2];     gf[1] = rd[3];
        }

        // combined-rcp cell update (round-6 math), 2 cells
        float ei[2], ef[2], eg[2], eo[2];
        #pragma unroll
        for (int rr = 0; rr < 2; ++rr) {
            ei[rr] = __expf(-gi[rr]);
            ef[rr] = __expf(-gf[rr]);
            eg[rr] = __expf(-2.f * gg[rr]);
            eo[rr] = __expf(-go[rr]);
        }
        #pragma unroll
        for (int rr = 0; rr < 2; ++rr) {
            const float di = 1.f + ei[rr], df = 1.f + ef[rr];
            const float dg = 1.f + eg[rr], dd = 1.f + eo[rr];
            const float s1 = di * df, s2 = dg * dd;
            const float R  = rcpf(s1 * s2);
            const float Rs2 = R * s2, Rs1 = R * s1;
            const float si = Rs2 * df;               // sigm(i)
            const float sf = Rs2 * di;               // sigm(f)
            const float so = Rs1 * dg;               // sigm(o)
            const float tg = 2.f * (Rs1 * dd) - 1.f; // tanh(g)
            const float cf = sf * cst[rr] + si * tg;
            cst[rr] = cf;
            const float h = so * tanhr(cf);
            sHw[(quad * 4 + half * 2 + rr) * SHSTR + j] = f2bf(h);
        }

        if (half == 1) {                        // matrix filler post-B1
            ACCX_AND_PREFETCH
            if (t > 0) GN_TILE(t - 1)
        }

        // B2: h(t) visible
        __builtin_amdgcn_sched_barrier(0);
        asm volatile("s_waitcnt lgkmcnt(0)" ::: "memory");
        __builtin_amdgcn_s_barrier();
        __builtin_amdgcn_sched_barrier(0);
    }

    // epilogue: note-gate tile for t = T-1 (h(127) sits in sH[0]; duty wave 15)
    {
        const unsigned short* sHr = sH[T_ & 1];
        short8 ah[4];
        #pragma unroll
        for (int kt = 0; kt < 4; ++kt)
            ah[kt] = *(const short8*)(sHr + m16 * SHSTR + kt * 32 + quad * 8);
        GN_TILE(T_ - 1)
    }
}

// ---------------------------------------------------------------------------
// Note-LSTM recurrence on precomputed pre-activations.
// One thread per (b,t) sequence.  Gate order g: 0,1=i 2,3=f 4,5=g 6,7=o.
// ---------------------------------------------------------------------------
__global__ __launch_bounds__(64) void note_out_kernel(
    const float* __restrict__ Gn,    // [SEQ2_][NOTES][8] f32
    const float* __restrict__ Whh,   // [8][2] f32
    float* __restrict__ out)         // [B][T][156] f32
{
    const int q = blockIdx.x * 64 + threadIdx.x;
    if (q >= SEQ2_) return;

    float w0[8], w1[8];
    #pragma unroll
    for (int g = 0; g < 8; ++g) { w0[g] = Whh[g * 2]; w1[g] = Whh[g * 2 + 1]; }

    const float* gp = Gn + (size_t)q * (NOTES_ * 8);
    float* op = out + (size_t)q * (NOTES_ * 2);

    float h0 = 0.f, h1 = 0.f, c0 = 0.f, c1 = 0.f;
    f32x4 ga = *(const f32x4*)(gp);
    f32x4 gb = *(const f32x4*)(gp + 4);
    for (int n = 0; n < NOTES_; ++n) {
        f32x4 na, nb;
        if (n + 1 < NOTES_) {
            na = *(const f32x4*)(gp + (n + 1) * 8);
            nb = *(const f32x4*)(gp + (n + 1) * 8 + 4);
        }
        const float i0 = ga[0] + w0[0] * h0 + w1[0] * h1;
        const float i1 = ga[1] + w0[1] * h0 + w1[1] * h1;
        const float f0 = ga[2] + w0[2] * h0 + w1[2] * h1;
        const float f1 = ga[3] + w0[3] * h0 + w1[3] * h1;
        const float g0 = gb[0] + w0[4] * h0 + w1[4] * h1;
        const float g1 = gb[1] + w0[5] * h0 + w1[5] * h1;
        const float o0 = gb[2] + w0[6] * h0 + w1[6] * h1;
        const float o1 = gb[3] + w0[7] * h0 + w1[7] * h1;
        c0 = sigm(f0) * c0 + sigm(i0) * tanhr(g0);
        c1 = sigm(f1) * c1 + sigm(i1) * tanhr(g1);
        h0 = sigm(o0) * tanhr(c0);
        h1 = sigm(o1) * tanhr(c1);
        op[n * 2 + 0] = h0;
        op[n * 2 + 1] = h1;
        ga = na; gb = nb;
    }
}

extern "C" void kernel_launch(void* const* d_in, const int* in_sizes, int n_in,
                              void* d_out, int out_size, void* d_ws, size_t ws_size,
                              hipStream_t stream) {
    const float* x     = (const float*)d_in[0];
    const float* Wih_t = (const float*)d_in[1];
    const float* Whh_t = (const float*)d_in[2];
    const float* bih_t = (const float*)d_in[3];
    const float* bhh_t = (const float*)d_in[4];
    const float* Wih_n = (const float*)d_in[5];
    const float* Whh_n = (const float*)d_in[6];
    const float* bih_n = (const float*)d_in[7];
    const float* bhh_n = (const float*)d_in[8];
    float* out = (float*)d_out;

    const size_t xb_bytes = (size_t)NSEQ_ * T_ * IN_ * 2;          // 51.1 MB
    const size_t gn_bytes = (size_t)SEQ2_ * NOTES_ * 8 * 4;        // 10.2 MB

    if (ws_size >= xb_bytes + gn_bytes) {
        // Layout: [xb16 51.1MB][Gn 10.2MB]
        unsigned short* xb = (unsigned short*)d_ws;
        float* Gn = (float*)((char*)d_ws + xb_bytes);
        xcvt_kernel<<<(XN8 + 255) / 256, 256, 0, stream>>>(x, xb);
        time_lstm_kernel<true><<<NBLK1, 1024, 0, stream>>>(
            xb, Wih_t, Whh_t, bih_t, bhh_t, Wih_n, bih_n, bhh_n, Gn);
        note_out_kernel<<<SEQ2_ / 64, 64, 0, stream>>>(Gn, Whh_n, out);
    } else {
        // Fallback: no x pre-convert; Gn at ws base.
        float* Gn = (float*)d_ws;
        time_lstm_kernel<false><<<NBLK1, 1024, 0, stream>>>(
            x, Wih_t, Whh_t, bih_t, bhh_t, Wih_n, bih_n, bhh_n, Gn);
        note_out_kernel<<<SEQ2_ / 64, 64, 0, stream>>>(Gn, Whh_n, out);
    }
}

// Round 8
// 354.274 us; speedup vs baseline: 1.3638x; 1.3638x over previous
//
#include <hip/hip_runtime.h>

// Problem constants
#define B_     32
#define NOTES_ 78
#define T_     128
#define IN_    80
#define H_     128
#define NSEQ_  (B_*NOTES_)    // 2496
#define MBLK   16             // sequences per block (A-tile rows of 16x16x32 MFMA)
#define NBLK1  (NSEQ_/MBLK)   // 156 blocks
#define SEQ2_  (B_*T_)        // 4096 note-LSTM sequences
#define XN8    (NSEQ_*T_*IN_/8)
#define SHSTR  136            // sH row stride in shorts (272 B, 16B-aligned for b128)
#define SAXSTR 20             // accX col stride in floats (80 B: 16B-aligned, bank-spread)

typedef __attribute__((ext_vector_type(8))) short short8;   // 8 x bf16 (4 VGPRs)
typedef __attribute__((ext_vector_type(4))) float f32x4;

__device__ __forceinline__ unsigned short f2bf(float f) {
    unsigned u; __builtin_memcpy(&u, &f, 4);
    u += 0x7fffu + ((u >> 16) & 1u);          // RNE
    return (unsigned short)(u >> 16);
}
__device__ __forceinline__ short8 pack8(const float* p) {   // init-time only
    short8 r;
    #pragma unroll
    for (int k = 0; k < 8; ++k) r[k] = (short)f2bf(p[k]);
    return r;
}
__device__ __forceinline__ float rcpf(float x)  { return __builtin_amdgcn_rcpf(x); }
__device__ __forceinline__ float sigm(float x)  { return rcpf(1.f + __expf(-x)); }
__device__ __forceinline__ float tanhr(float x) { return 2.f * rcpf(1.f + __expf(-2.f*x)) - 1.f; }

// ---------------------------------------------------------------------------
// Phase A: convert x f32 -> bf16 (memory-bound, ~153 MB traffic, ~27 us).
// ---------------------------------------------------------------------------
__global__ __launch_bounds__(256) void xcvt_kernel(
    const float* __restrict__ x, unsigned short* __restrict__ xb)
{
    const int i = blockIdx.x * 256 + threadIdx.x;
    if (i < XN8) {
        const f32x4 a = *(const f32x4*)(x + (size_t)i * 8);
        const f32x4 b = *(const f32x4*)(x + (size_t)i * 8 + 4);
        short8 r;
        #pragma unroll
        for (int k = 0; k < 4; ++k) { r[k] = (short)f2bf(a[k]); r[4+k] = (short)f2bf(b[k]); }
        *(short8*)(xb + (size_t)i * 8) = r;
    }
}

// ---------------------------------------------------------------------------
// Fused time LSTM + note-gate pre-activations.
//
// THIS ROUND: 12 waves / 768 thr / block = 3 waves per SIMD:
//   - waves 0-7  = COMPUTE: exactly round-6's structure (wave owns 16 h-cols
//     x 4 gates, 4-cell combined-rcp update) but with NO x-side work: acc
//     initializes from an LDS-staged accX tile (4 ds_reads), so wf weights,
//     ax loads and the accX MFMAs all leave the compute waves.
//   - waves 8-11 = HELPER (one per SIMD): helper u owns gate u's 128 cols,
//     holds its Wih fragments (96 regs), loads x one step ahead, computes
//     accX(t+1) = bias + x(t+1).Wih^T (24 MFMAs) and stages it to a
//     double-buffered LDS tile.  Helper work is h-independent -> it fills
//     the compute waves' stall cycles on the same SIMD.
// Register model (from r6/r7 evidence): allocator budget = 512/ceil(waves/4)
// per wave; 12 waves -> 170.  compute ~130, helper ~156: both fit, no spill.
// ONE raw lgkmcnt-only barrier per step (sH and accX both double-buffered;
// global x traffic never drains at the barrier).
// ---------------------------------------------------------------------------

// Note-gate tile for step TM1 (duty rotates over the 8 compute waves);
// wn read from LDS, output addressing recomputed in-branch.
#define GN_TILE(TM1)                                                                   \
    if (wave == ((TM1) & 7)) {                                                         \
        short8 wnk[4];                                                                 \
        _Pragma("unroll")                                                              \
        for (int kt = 0; kt < 4; ++kt)                                                 \
            wnk[kt] = *(const short8*)(sWn + ((kt * 16 + m16) * 4 + quad) * 8);        \
        f32x4 an = (f32x4){0.f, 0.f, 0.f, 0.f};                                        \
        _Pragma("unroll")                                                              \
        for (int kt = 0; kt < 4; ++kt)                                                 \
            an = __builtin_amdgcn_mfma_f32_16x16x32_bf16(ah[kt], wnk[kt], an, 0, 0, 0);\
        if (m16 < 8) {                                                                 \
            _Pragma("unroll")                                                          \
            for (int r = 0; r < 4; ++r) {                                              \
                const int sq = seq0 + quad * 4 + r;                                    \
                const int bb = sq / NOTES_;                                            \
                const int nn = sq - bb * NOTES_;                                       \
                Gn[((unsigned)bb * (T_ * NOTES_) + (unsigned)nn) * 8u + (unsigned)m16  \
                   + (unsigned)(TM1) * (NOTES_ * 8)] = an[r] + bns;                    \
            }                                                                          \
        }                                                                              \
    }

template<bool XB16>
__global__ __launch_bounds__(768)
void time_lstm_kernel(
    const void* __restrict__ xin,    // [NSEQ][T][IN] bf16 (XB16) or f32
    const float* __restrict__ Wih,   // [512][80]  f32
    const float* __restrict__ Whh,   // [512][128] f32
    const float* __restrict__ bih,   // [512] f32
    const float* __restrict__ bhh,   // [512] f32
    const float* __restrict__ Wn,    // [8][128] f32 (Wih_n)
    const float* __restrict__ bn1,   // [8] f32
    const float* __restrict__ bn2,   // [8] f32
    float* __restrict__ Gn)          // [B*T][NOTES][8] f32 (ws)
{
    __shared__ unsigned short sH[2][MBLK * SHSTR];   //  8704 B, double-buffered h
    __shared__ float sAx[2][512 * SAXSTR];           // 81920 B, double-buffered accX
    __shared__ unsigned short sWn[4 * 16 * 4 * 8];   //  4096 B, note-gate weights

    const int tid  = threadIdx.x;
    const int wave = tid >> 6, lane = tid & 63;
    const int m16  = lane & 15, quad = lane >> 4;
    const int seq0 = blockIdx.x * MBLK;

    for (int i = tid; i < 2 * MBLK * SHSTR; i += 768)
        ((unsigned short*)sH)[i] = 0;          // h(-1) = 0
    for (int i = tid; i < 4 * 16 * 4 * 8; i += 768) {
        const int e = i & 7, qq = (i >> 3) & 3, m = (i >> 5) & 15, kt = i >> 9;
        sWn[i] = (m < 8) ? f2bf(Wn[m * H_ + kt * 32 + qq * 8 + e]) : (unsigned short)0;
    }

    const short8 zero8 = (short8){0,0,0,0,0,0,0,0};
    const float bns = (m16 < 8) ? (bn1[m16] + bn2[m16]) : 0.f;

    if (wave < 8) {
        // =================== COMPUTE WAVE (round-6 core, x-free) ===========
        const int j = wave * 16 + m16;         // this lane's h-column

        short8 hf[4][4];
        #pragma unroll
        for (int g = 0; g < 4; ++g) {
            const int n = g * H_ + j;
            #pragma unroll
            for (int kt = 0; kt < 4; ++kt)
                hf[g][kt] = pack8(Whh + n * H_ + kt * 32 + quad * 8);
        }
        float cst[4] = {0.f, 0.f, 0.f, 0.f};

        __syncthreads();                        // init fence

        for (int t = 0; t < T_; ++t) {
            const unsigned short* sHr = sH[t & 1];
            unsigned short*       sHw = sH[(t & 1) ^ 1];
            const float*          axr = sAx[t & 1];

            // h(t-1) A-fragments
            short8 ah[4];
            #pragma unroll
            for (int kt = 0; kt < 4; ++kt)
                ah[kt] = *(const short8*)(sHr + m16 * SHSTR + kt * 32 + quad * 8);

            // gate acc: init from staged accX (bias + x-part), 4-deep h chain
            f32x4 acc[4];
            #pragma unroll
            for (int g = 0; g < 4; ++g)
                acc[g] = *(const f32x4*)(axr + (g * H_ + j) * SAXSTR + quad * 4);
            __builtin_amdgcn_s_setprio(1);
            #pragma unroll
            for (int g = 0; g < 4; ++g) {
                #pragma unroll
                for (int kt = 0; kt < 4; ++kt)
                    acc[g] = __builtin_amdgcn_mfma_f32_16x16x32_bf16(ah[kt], hf[g][kt], acc[g], 0, 0, 0);
            }
            __builtin_amdgcn_s_setprio(0);

            // note-gate tile for step t-1 (duty 1/8, uses same ah)
            if (t > 0) GN_TILE(t - 1)

            // combined-rcp cell update (round-6 math), 4 cells
            float ei[4], ef[4], eg[4], eo[4];
            #pragma unroll
            for (int r = 0; r < 4; ++r) {
                ei[r] = __expf(-acc[0][r]);
                ef[r] = __expf(-acc[1][r]);
                eg[r] = __expf(-2.f * acc[2][r]);
                eo[r] = __expf(-acc[3][r]);
            }
            #pragma unroll
            for (int r = 0; r < 4; ++r) {
                const float di = 1.f + ei[r], df = 1.f + ef[r];
                const float dg = 1.f + eg[r], dd = 1.f + eo[r];
                const float s1 = di * df, s2 = dg * dd;
                const float R  = rcpf(s1 * s2);
                const float Rs2 = R * s2, Rs1 = R * s1;
                const float si = Rs2 * df;               // sigm(i)
                const float sf = Rs2 * di;               // sigm(f)
                const float so = Rs1 * dg;               // sigm(o)
                const float tg = 2.f * (Rs1 * dd) - 1.f; // tanh(g)
                const float cf = sf * cst[r] + si * tg;
                cst[r] = cf;
                const float h = so * tanhr(cf);
                sHw[(quad * 4 + r) * SHSTR + j] = f2bf(h);
            }

            // ONE barrier per step (lgkmcnt only; rule #18 sched fences)
            __builtin_amdgcn_sched_barrier(0);
            asm volatile("s_waitcnt lgkmcnt(0)" ::: "memory");
            __builtin_amdgcn_s_barrier();
            __builtin_amdgcn_sched_barrier(0);
        }

        // epilogue: note-gate tile for t = T-1 (h(127) sits in sH[0])
        {
            const unsigned short* sHr = sH[T_ & 1];
            short8 ah[4];
            #pragma unroll
            for (int kt = 0; kt < 4; ++kt)
                ah[kt] = *(const short8*)(sHr + m16 * SHSTR + kt * 32 + quad * 8);
            GN_TILE(T_ - 1)
        }
    } else {
        // =================== HELPER WAVE (x-side producer) =================
        const int u = wave - 8;                // owns gate u's 128 columns

        short8 wfh[8][3];
        float  bg8[8];
        #pragma unroll
        for (int nt = 0; nt < 8; ++nt) {
            const int n = u * H_ + nt * 16 + m16;   // gate-col in [128u,128u+128)
            #pragma unroll
            for (int kt = 0; kt < 3; ++kt) {
                const int k = kt * 32 + quad * 8;
                wfh[nt][kt] = (k < IN_) ? pack8(Wih + n * IN_ + k) : zero8;
            }
            bg8[nt] = bih[n] + bhh[n];
        }

        const float* xrf = XB16 ? nullptr
            : ((const float*)xin + (size_t)(seq0 + m16) * T_ * IN_);
        const unsigned short* xrb = XB16
            ? ((const unsigned short*)xin + (size_t)(seq0 + m16) * T_ * IN_) : nullptr;

        short8 ax0, ax1, ax2 = zero8;
        // load x(0)
        if (XB16) {
            const unsigned short* p = xrb;
            ax0 = *(const short8*)(p + quad * 8);
            ax1 = *(const short8*)(p + 32 + quad * 8);
            if (quad < 2) ax2 = *(const short8*)(p + 64 + quad * 8);
        } else {
            const float* p = xrf;
            ax0 = pack8(p + quad * 8);
            ax1 = pack8(p + 32 + quad * 8);
            if (quad < 2) ax2 = pack8(p + 64 + quad * 8);
        }
        // prologue: accX(0) -> sAx[0]
        {
            float* wp = sAx[0];
            #pragma unroll
            for (int nt = 0; nt < 8; ++nt) {
                f32x4 a8 = (f32x4){bg8[nt], bg8[nt], bg8[nt], bg8[nt]};
                a8 = __builtin_amdgcn_mfma_f32_16x16x32_bf16(ax0, wfh[nt][0], a8, 0, 0, 0);
                a8 = __builtin_amdgcn_mfma_f32_16x16x32_bf16(ax1, wfh[nt][1], a8, 0, 0, 0);
                a8 = __builtin_amdgcn_mfma_f32_16x16x32_bf16(ax2, wfh[nt][2], a8, 0, 0, 0);
                *(f32x4*)(wp + (u * H_ + nt * 16 + m16) * SAXSTR + quad * 4) = a8;
            }
        }
        // load x(1)
        if (XB16) {
            const unsigned short* p = xrb + IN_;
            ax0 = *(const short8*)(p + quad * 8);
            ax1 = *(const short8*)(p + 32 + quad * 8);
            if (quad < 2) ax2 = *(const short8*)(p + 64 + quad * 8);
        } else {
            const float* p = xrf + IN_;
            ax0 = pack8(p + quad * 8);
            ax1 = pack8(p + 32 + quad * 8);
            if (quad < 2) ax2 = pack8(p + 64 + quad * 8);
        }

        __syncthreads();                        // init fence

        for (int t = 0; t < T_; ++t) {
            // accX(t+1) = bias + x(t+1).Wih^T  -> sAx[(t+1)&1]
            if (t + 1 < T_) {
                float* wp = sAx[(t + 1) & 1];
                #pragma unroll
                for (int nt = 0; nt < 8; ++nt) {
                    f32x4 a8 = (f32x4){bg8[nt], bg8[nt], bg8[nt], bg8[nt]};
                    a8 = __builtin_amdgcn_mfma_f32_16x16x32_bf16(ax0, wfh[nt][0], a8, 0, 0, 0);
                    a8 = __builtin_amdgcn_mfma_f32_16x16x32_bf16(ax1, wfh[nt][1], a8, 0, 0, 0);
                    a8 = __builtin_amdgcn_mfma_f32_16x16x32_bf16(ax2, wfh[nt][2], a8, 0, 0, 0);
                    *(f32x4*)(wp + (u * H_ + nt * 16 + m16) * SAXSTR + quad * 4) = a8;
                }
            }
            // prefetch x(t+2): full-step window; never drained at barrier
            if (t + 2 < T_) {
                if (XB16) {
                    const unsigned short* p = xrb + (t + 2) * IN_;
                    ax0 = *(const short8*)(p + quad * 8);
                    ax1 = *(const short8*)(p + 32 + quad * 8);
                    if (quad < 2) ax2 = *(const short8*)(p + 64 + quad * 8);
                } else {
                    const float* p = xrf + (t + 2) * IN_;
                    ax0 = pack8(p + quad * 8);
                    ax1 = pack8(p + 32 + quad * 8);
                    if (quad < 2) ax2 = pack8(p + 64 + quad * 8);
                }
            }

            __builtin_amdgcn_sched_barrier(0);
            asm volatile("s_waitcnt lgkmcnt(0)" ::: "memory");
            __builtin_amdgcn_s_barrier();
            __builtin_amdgcn_sched_barrier(0);
        }
    }
}

// ---------------------------------------------------------------------------
// Note-LSTM recurrence on precomputed pre-activations.
// One thread per (b,t) sequence.  Gate order g: 0,1=i 2,3=f 4,5=g 6,7=o.
// ---------------------------------------------------------------------------
__global__ __launch_bounds__(64) void note_out_kernel(
    const float* __restrict__ Gn,    // [SEQ2_][NOTES][8] f32
    const float* __restrict__ Whh,   // [8][2] f32
    float* __restrict__ out)         // [B][T][156] f32
{
    const int q = blockIdx.x * 64 + threadIdx.x;
    if (q >= SEQ2_) return;

    float w0[8], w1[8];
    #pragma unroll
    for (int g = 0; g < 8; ++g) { w0[g] = Whh[g * 2]; w1[g] = Whh[g * 2 + 1]; }

    const float* gp = Gn + (size_t)q * (NOTES_ * 8);
    float* op = out + (size_t)q * (NOTES_ * 2);

    float h0 = 0.f, h1 = 0.f, c0 = 0.f, c1 = 0.f;
    f32x4 ga = *(const f32x4*)(gp);
    f32x4 gb = *(const f32x4*)(gp + 4);
    for (int n = 0; n < NOTES_; ++n) {
        f32x4 na, nb;
        if (n + 1 < NOTES_) {
            na = *(const f32x4*)(gp + (n + 1) * 8);
            nb = *(const f32x4*)(gp + (n + 1) * 8 + 4);
        }
        const float i0 = ga[0] + w0[0] * h0 + w1[0] * h1;
        const float i1 = ga[1] + w0[1] * h0 + w1[1] * h1;
        const float f0 = ga[2] + w0[2] * h0 + w1[2] * h1;
        const float f1 = ga[3] + w0[3] * h0 + w1[3] * h1;
        const float g0 = gb[0] + w0[4] * h0 + w1[4] * h1;
        const float g1 = gb[1] + w0[5] * h0 + w1[5] * h1;
        const float o0 = gb[2] + w0[6] * h0 + w1[6] * h1;
        const float o1 = gb[3] + w0[7] * h0 + w1[7] * h1;
        c0 = sigm(f0) * c0 + sigm(i0) * tanhr(g0);
        c1 = sigm(f1) * c1 + sigm(i1) * tanhr(g1);
        h0 = sigm(o0) * tanhr(c0);
        h1 = sigm(o1) * tanhr(c1);
        op[n * 2 + 0] = h0;
        op[n * 2 + 1] = h1;
        ga = na; gb = nb;
    }
}

extern "C" void kernel_launch(void* const* d_in, const int* in_sizes, int n_in,
                              void* d_out, int out_size, void* d_ws, size_t ws_size,
                              hipStream_t stream) {
    const float* x     = (const float*)d_in[0];
    const float* Wih_t = (const float*)d_in[1];
    const float* Whh_t = (const float*)d_in[2];
    const float* bih_t = (const float*)d_in[3];
    const float* bhh_t = (const float*)d_in[4];
    const float* Wih_n = (const float*)d_in[5];
    const float* Whh_n = (const float*)d_in[6];
    const float* bih_n = (const float*)d_in[7];
    const float* bhh_n = (const float*)d_in[8];
    float* out = (float*)d_out;

    const size_t xb_bytes = (size_t)NSEQ_ * T_ * IN_ * 2;          // 51.1 MB
    const size_t gn_bytes = (size_t)SEQ2_ * NOTES_ * 8 * 4;        // 10.2 MB

    if (ws_size >= xb_bytes + gn_bytes) {
        // Layout: [xb16 51.1MB][Gn 10.2MB]
        unsigned short* xb = (unsigned short*)d_ws;
        float* Gn = (float*)((char*)d_ws + xb_bytes);
        xcvt_kernel<<<(XN8 + 255) / 256, 256, 0, stream>>>(x, xb);
        time_lstm_kernel<true><<<NBLK1, 768, 0, stream>>>(
            xb, Wih_t, Whh_t, bih_t, bhh_t, Wih_n, bih_n, bhh_n, Gn);
        note_out_kernel<<<SEQ2_ / 64, 64, 0, stream>>>(Gn, Whh_n, out);
    } else {
        // Fallback: no x pre-convert; Gn at ws base.
        float* Gn = (float*)d_ws;
        time_lstm_kernel<false><<<NBLK1, 768, 0, stream>>>(
            x, Wih_t, Whh_t, bih_t, bhh_t, Wih_n, bih_n, bhh_n, Gn);
        note_out_kernel<<<SEQ2_ / 64, 64, 0, stream>>>(Gn, Whh_n, out);
    }
}